// Round 16
// baseline (293.209 us; speedup 1.0000x reference)
//
#include <hip/hip_runtime.h>
#include <math.h>

// Problem constants
#define BB 2
#define CC 128
#define NN 4096            // D*H*W = 16*16*16
#define EE 46              // 16 + 15 + 15 neighbors
#define FS 48              // axis-major f stride: col = axis*16 + slot
#define DS 64              // DSIM = PSIM = GDIM = 64
#define CPAD 16            // dwords per shadow slot (one 64B line each)
#define NSH 16             // shadow copies per counter (atomic de-contention)
// colnorm layout: [b][e][NSH][CPAD] -> addr ((b*EE+e)*NSH + s)*CPAD

// ===========================================================================
// Setup: zero colnorms, geo projections, h transpose. grid 512 x 256.
__global__ __launch_bounds__(256) void k_setup(
    const float* __restrict__ x,
    const float* __restrict__ gt_w, const float* __restrict__ gt_b,
    const float* __restrict__ gp_w, const float* __restrict__ gp_b,
    float* __restrict__ p_theta, float* __restrict__ p_phi,
    float* __restrict__ colnorm_p, float* __restrict__ colnorm_f,
    float* __restrict__ h)
{
    __shared__ float xs[32 * 65];
    const int t = threadIdx.x, bid = blockIdx.x;
    const int gtid = bid * 256 + t;

    if (gtid < EE * NSH * CPAD) colnorm_p[gtid] = 0.f;
    if (gtid < 3 * BB * EE * NSH * CPAD) colnorm_f[gtid] = 0.f;

    for (int idx = gtid; idx < NN * DS; idx += 512 * 256) {
        int n = idx >> 6, s = idx & 63;
        int i = n >> 8, j = (n >> 4) & 15, k = n & 15;
        float p0 = i * (1.f / 15.f) - 0.5f;
        float p1 = j * (1.f / 15.f) - 0.5f;
        float p2 = k * (1.f / 15.f) - 0.5f;
        p_theta[idx] = p0 * gt_w[s * 3] + p1 * gt_w[s * 3 + 1] + p2 * gt_w[s * 3 + 2] + gt_b[s];
        p_phi[idx]   = p0 * gp_w[s * 3] + p1 * gp_w[s * 3 + 1] + p2 * gp_w[s * 3 + 2] + gp_b[s];
    }
    {   // h[b][n][c] = x[b][c][n], one 64n x 32c tile per block
        int n0 = (bid & 63) * 64, c0 = ((bid >> 6) & 3) * 32, b = bid >> 8;
        for (int q = t; q < 2048; q += 256) {
            int cl = q >> 6, nl = q & 63;
            xs[cl * 65 + nl] = x[(size_t)(b * CC + c0 + cl) * NN + n0 + nl];
        }
        __syncthreads();
        for (int q = t; q < 2048; q += 256) {
            int nl = q >> 5, cl = q & 31;
            h[(size_t)(b * NN + n0 + nl) * CC + c0 + cl] = xs[cl * 65 + nl];
        }
    }
}

// ===========================================================================
// proj: [8192x128]x[128x192]^T GEMM. 32-row x 64-col tiles, BOTH operands
// LDS-staged (48 KB -> 3 blocks/CU), XOR-swizzled, 2x4 register blocking.
__global__ __launch_bounds__(256) void k_proj(
    const float* __restrict__ h,
    const float* __restrict__ th_w, const float* __restrict__ th_b,
    const float* __restrict__ ph_w, const float* __restrict__ ph_b,
    const float* __restrict__ G_w,  const float* __restrict__ G_b,
    float* __restrict__ T, float* __restrict__ P, float* __restrict__ Gx)
{
    __shared__ __align__(16) float smf[12288];   // 48 KB
    const int t = threadIdx.x;
    const int row0 = (blockIdx.x & 255) * 32;
    const int cgp = blockIdx.x >> 8;
    const float* w    = cgp == 0 ? th_w : cgp == 1 ? ph_w : G_w;
    const float* bias = cgp == 0 ? th_b : cgp == 1 ? ph_b : G_b;
    float* o          = cgp == 0 ? T    : cgp == 1 ? P    : Gx;
    float4* hs4 = (float4*)smf;              // [32][32] f4, XOR-swizzled
    float4* ws4 = (float4*)smf + 1024;       // [64][32] f4, XOR-swizzled
    const float4* h4 = (const float4*)h;
    const float4* w4 = (const float4*)w;
    for (int q = t; q < 1024; q += 256) {
        int row = q >> 5, kc = q & 31;
        hs4[row * 32 + (kc ^ row)] = h4[(size_t)(row0 + row) * 32 + kc];
    }
    for (int q = t; q < 2048; q += 256) {
        int row = q >> 5, kc = q & 31;
        ws4[row * 32 + (kc ^ (row & 31))] = w4[q];
    }
    __syncthreads();
    const int rt = t >> 4, m = t & 15;       // rows 2rt,2rt+1; cols m+16i
    float acc[2][4] = {{0, 0, 0, 0}, {0, 0, 0, 0}};
    for (int kc = 0; kc < 32; ++kc) {
        float4 a0 = hs4[(2 * rt) * 32 + (kc ^ (2 * rt))];
        float4 a1 = hs4[(2 * rt + 1) * 32 + (kc ^ (2 * rt + 1))];
        float4 wv[4];
#pragma unroll
        for (int i = 0; i < 4; ++i) {
            int c = m + 16 * i;
            wv[i] = ws4[c * 32 + (kc ^ (c & 31))];
        }
#pragma unroll
        for (int i = 0; i < 4; ++i) {
            acc[0][i] += a0.x * wv[i].x + a0.y * wv[i].y
                       + a0.z * wv[i].z + a0.w * wv[i].w;
            acc[1][i] += a1.x * wv[i].x + a1.y * wv[i].y
                       + a1.z * wv[i].z + a1.w * wv[i].w;
        }
    }
#pragma unroll
    for (int i = 0; i < 4; ++i) {
        float bv = bias[m + 16 * i];
#pragma unroll
        for (int rr = 0; rr < 2; ++rr)
            o[(size_t)(row0 + 2 * rt + rr) * DS + m + 16 * i] = acc[rr][i] + bv;
    }
}

// ===========================================================================
// axis helpers
__device__ __forceinline__ int axis_node(int axis, int line, int s) {
    if (axis == 0) return s * 256 + line;                           // D: line=(j,k)
    if (axis == 1) return (line >> 4) * 256 + s * 16 + (line & 15); // H: line=(i,k)
    return line * 16 + s;                                           // W: line=(i,j)
}

// ===========================================================================
// k_fax: axis-decomposed f, AXIS-MAJOR storage f[b][n][48] (col=axis*16+slot).
// Coalesced LDS-staged dots; sorted rank e used only for per-e sumsq; global
// reduction to shadow slot (line & 15) -> per-address chain 48 (r15-verified).
__global__ __launch_bounds__(256) void k_fax(
    const float* __restrict__ T, const float* __restrict__ P,
    float* __restrict__ fax, float* __restrict__ colnorm)
{
    __shared__ __align__(16) float4 Ts4[272];    // [16][17]
    __shared__ __align__(16) float4 Ps4[272];
    __shared__ float sq[64];

    const int t = threadIdx.x;
    const int line = blockIdx.x, axis = blockIdx.y, b = blockIdx.z;
    {
        int s = t >> 4, kc = t & 15;
        int nrow = axis_node(axis, line, s);
        Ts4[s * 17 + kc] = ((const float4*)T)[((size_t)b * NN + nrow) * 16 + kc];
        Ps4[s * 17 + kc] = ((const float4*)P)[((size_t)b * NN + nrow) * 16 + kc];
    }
    if (t < 64) sq[t] = 0.f;
    __syncthreads();

    const int node = t >> 4, slot = t & 15;      // node-major: coalesced writes
    const int n = axis_node(axis, line, node);
    const int m = axis_node(axis, line, slot);
    const int jj = (n >> 4) & 15, kk = n & 15;
    bool valid = !((axis == 1 && slot == jj) || (axis == 2 && slot == kk));

    float dot = 0.f;
#pragma unroll
    for (int kc = 0; kc < 16; ++kc) {
        float4 a = Ts4[node * 17 + kc];
        float4 p = Ps4[slot * 17 + kc];
        dot += a.x * p.x + a.y * p.y + a.z * p.z + a.w * p.w;
    }

    if (valid) {
        fax[((size_t)b * NN + n) * FS + axis * 16 + slot] = dot;
        // sorted rank of m in n's merged neighbor list (for per-e sumsq)
        const int jk = n & 255, base = n & ~255;
        int d = m - jk;
        int cD = d <= 0 ? 0 : min(16, (d + 255) >> 8);
        int hd = m - base - kk;
        int cHr = hd <= 0 ? 0 : min(16, (hd + 15) >> 4);
        int cH = cHr - (jj < cHr ? 1 : 0);
        int wd = m - (n - kk);
        int cWr = wd <= 0 ? 0 : min(16, wd);
        int cW = cWr - (kk < cWr ? 1 : 0);
        int e = cD + cH + cW;
        atomicAdd(&sq[e], dot * dot);
    }
    __syncthreads();
    if (t < EE)
        atomicAdd(colnorm + ((size_t)(b * EE + t) * NSH + (line & (NSH - 1))) * CPAD,
                  sq[t]);
}

// ===========================================================================
// k_agg: axis-decomposed aggregation WITH FUSED r_w epilogue. Per (axis,
// line, b): softmax (sorted-space numerics, shadow colnorms summed) ->
// wmat scatter -> dense 16x16x64 y_axis (kept in LDS) -> delta_axis =
// y_axis @ r_w^T (rotation-swizzled LDS rw, 2x4 blocking) -> atomicAdd
// into h (delta is linear in y, so per-axis partials sum; r_b added by
// axis 0 only; 3-way contention per element = negligible per r15 model).
__global__ __launch_bounds__(256) void k_agg(
    const int* __restrict__ nbr2_unused,
    const float* __restrict__ f, const float* __restrict__ f_p,
    const float* __restrict__ colnorm_p, const float* __restrict__ colnorm_f,
    const float* __restrict__ Gx,
    const float* __restrict__ r_w, const float* __restrict__ r_b,
    float* __restrict__ h)
{
    __shared__ __align__(16) float smf[10688];   // 42752 B -> 3 blocks/CU
    float4* rws4 = (float4*)smf;                 // dw 0..8191 rot-swizzled
    float*  ys   = smf + 8192;                   // [16][68] dw 8192..9279
    float*  Gl   = smf + 9280;                   // [16][64] dw 9280..10303
    float*  wmat = smf + 10304;                  // [16][16] dw 10304..10559
    float*  nf   = smf + 10560;                  // 64
    float*  np   = smf + 10624;                  // 64

    const int t = threadIdx.x;
    const int line = blockIdx.x, axis = blockIdx.y, b = blockIdx.z;

    for (int i2 = t; i2 < 2048; i2 += 256) {
        int c = i2 >> 4, g4 = i2 & 15;
        rws4[c * 16 + ((g4 + c) & 15)] = ((const float4*)r_w)[i2];
    }
    if (t < EE) {
        float sf = 0.f, sp = 0.f;
#pragma unroll
        for (int s = 0; s < NSH; ++s) {
            sf += colnorm_f[((size_t)(b * EE + t) * NSH + s) * CPAD];
            sp += colnorm_p[((size_t)t * NSH + s) * CPAD];
        }
        nf[t] = 1.f / (1e-6f + sqrtf(sf));
        np[t] = 1.f / (1e-6f + sqrtf(sp));
    }
    wmat[t] = 0.f;
    {
        int s = t >> 4, c4 = t & 15;
        int nrow = axis_node(axis, line, s);
        ((float4*)Gl)[s * 16 + c4] =
            ((const float4*)Gx)[((size_t)b * NN + nrow) * 16 + c4];
    }
    __syncthreads();

    const int wv = t >> 6, l = t & 63;
    for (int ii = 0; ii < 4; ++ii) {
        int sn = wv * 4 + ii;
        int n = axis_node(axis, line, sn);
        float fvv = -INFINITY; int ax = 0, slot = 0;
        if (l < EE) {
            // reconstruct sorted neighbor l of n arithmetically? keep the
            // verified path: classify via nbr-free mapping below needs m;
            // instead read f/f_p axis-major through the (ax,slot) decode of
            // the sorted index l using the inverse rank walk is costly —
            // so we reuse the proven approach: iterate sorted l via table-
            // free classification requires m; we recompute m from (n, l)
            // with a 3-way merge step count. Cheaper: the nbr table is
            // still available globally? We dropped it. Use merge-walk:
            // compute the l-th smallest among the 3 axis lists.
            // D list: vals jk + 256*s (s=0..15); H: base+16*s'+kk (s'!=jj);
            // W: n-kk+s'' (s''!=kk). All comparable by value; find l-th.
            // Binary search over value space is overkill; do a 3-pointer
            // count: for candidate value v the rank is monotone. Instead
            // walk: rank(v) counts computed arithmetically; invert by
            // trying each of the 46 values is serial. Simplest correct:
            // reconstruct via the same counting used in k_fax, inverted:
            // for each of my 46 candidates I know its rank; so thread l
            // needs the candidate whose rank == l. Do it cooperatively:
            // each lane computes rank of ONE candidate and scatters.
            fvv = 0.f; // placeholder, real work below
        }
        // ---- cooperative sorted-index construction (lanes 0..45 hold one
        // candidate each: 0..15 -> D slot, 16..30 -> H slots skipping jj,
        // 31..45 -> W slots skipping kk), compute its sorted rank, scatter
        // value+id into rank-indexed LDS-free via shuffle variables.
        int cand_ax = 0, cand_slot = 0;
        if (l < 16)      { cand_ax = 0; cand_slot = l; }
        else if (l < 31) { int s2 = l - 16; cand_ax = 1; cand_slot = s2 + (s2 >= ((n >> 4) & 15) ? 1 : 0); }
        else if (l < EE) { int s2 = l - 31; cand_ax = 2; cand_slot = s2 + (s2 >= (n & 15) ? 1 : 0); }
        int m = axis_node(cand_ax, (cand_ax == 0) ? (n & 255)
                   : (cand_ax == 1) ? (((n >> 8) << 4) | (n & 15))
                   : (n >> 4), cand_slot);
        int e_rank = 0;
        if (l < EE) {
            const int jj2 = (n >> 4) & 15, kk2 = n & 15;
            const int jk = n & 255, base = n & ~255;
            int d = m - jk;
            int cD = d <= 0 ? 0 : min(16, (d + 255) >> 8);
            int hd = m - base - kk2;
            int cHr = hd <= 0 ? 0 : min(16, (hd + 15) >> 4);
            int cH = cHr - (jj2 < cHr ? 1 : 0);
            int wd = m - (n - kk2);
            int cWr = wd <= 0 ? 0 : min(16, wd);
            int cW = cWr - (kk2 < cWr ? 1 : 0);
            e_rank = cD + cH + cW;
        }
        // candidate l's data, to be consumed at sorted position e_rank:
        // value from axis-major f/f_p at (cand_ax,cand_slot)
        float fval = 0.f, fpval = 0.f;
        if (l < EE) {
            int col = cand_ax * 16 + cand_slot;
            fval  = f[(size_t)(b * NN + n) * FS + col];
            fpval = f_p[(size_t)n * FS + col];
        }
        // scatter into sorted order via LDS (reuse ys region transiently)
        float* perm = ys;                        // [3][64] scratch per wave
        float* pv = perm + wv * 68;              // safe: ys is [16][68]
        // store (fval, fpval, ax, slot) keyed by rank — pack two passes
        if (l < EE) pv[e_rank] = fval;
        __builtin_amdgcn_wave_barrier();
        float f_sorted = (l < EE) ? pv[l] : 0.f;
        __builtin_amdgcn_wave_barrier();
        if (l < EE) pv[e_rank] = fpval;
        __builtin_amdgcn_wave_barrier();
        float fp_sorted = (l < EE) ? pv[l] : 0.f;
        __builtin_amdgcn_wave_barrier();
        if (l < EE) pv[e_rank] = (float)(cand_ax * 16 + cand_slot);
        __builtin_amdgcn_wave_barrier();
        int col_sorted = (l < EE) ? (int)pv[l] : 0;
        __builtin_amdgcn_wave_barrier();

        if (l < EE) {
            float fpv2 = fp_sorted * np[l];
            fpv2 = fpv2 > 0.f ? fpv2 : 0.f;
            fvv = f_sorted * nf[l] + fpv2;
            ax = col_sorted >> 4; slot = col_sorted & 15;
        }
        float mx = fvv;
        for (int o = 32; o; o >>= 1) mx = fmaxf(mx, __shfl_down(mx, o));
        mx = __shfl(mx, 0);
        float ex = (l < EE) ? expf(fvv - mx) : 0.f;
        float sm = ex;
        for (int o = 32; o; o >>= 1) sm += __shfl_down(sm, o);
        sm = __shfl(sm, 0);
        if (l < EE && ax == axis) wmat[sn * 16 + slot] = ex / sm;
        __builtin_amdgcn_wave_barrier();
    }
    __syncthreads();

    // dense 16x16x64 -> y_axis into ys [16][68]
    {
        float acc[4] = {0.f, 0.f, 0.f, 0.f};
        for (int s = 0; s < 16; ++s) {
            float gv = Gl[s * 64 + l];
            acc[0] += wmat[(wv * 4 + 0) * 16 + s] * gv;
            acc[1] += wmat[(wv * 4 + 1) * 16 + s] * gv;
            acc[2] += wmat[(wv * 4 + 2) * 16 + s] * gv;
            acc[3] += wmat[(wv * 4 + 3) * 16 + s] * gv;
        }
#pragma unroll
        for (int kk = 0; kk < 4; ++kk)
            ys[(wv * 4 + kk) * 68 + l] = acc[kk];
    }
    __syncthreads();

    // fused epilogue: delta[16][128] = ys @ rw^T, atomicAdd into h
    const int r0 = (t >> 5) * 2, cl = t & 31;
    float4* ys4 = (float4*)ys;                   // row stride 17 f4
    float acc2[2][4] = {{0, 0, 0, 0}, {0, 0, 0, 0}};
    for (int g4 = 0; g4 < 16; ++g4) {
        float4 ya = ys4[r0 * 17 + g4];
        float4 yb = ys4[(r0 + 1) * 17 + g4];
#pragma unroll
        for (int cc = 0; cc < 4; ++cc) {
            int c = cl + 32 * cc;
            float4 w = rws4[c * 16 + ((g4 + c) & 15)];
            acc2[0][cc] += ya.x * w.x + ya.y * w.y + ya.z * w.z + ya.w * w.w;
            acc2[1][cc] += yb.x * w.x + yb.y * w.y + yb.z * w.z + yb.w * w.w;
        }
    }
#pragma unroll
    for (int rr = 0; rr < 2; ++rr) {
        int n = axis_node(axis, line, r0 + rr);
        size_t bn = (size_t)b * NN + n;
#pragma unroll
        for (int cc = 0; cc < 4; ++cc) {
            int c = cl + 32 * cc;
            float add = acc2[rr][cc] + (axis == 0 ? r_b[c] : 0.f);
            atomicAdd(&h[bn * CC + c], add);
        }
    }
}

// ===========================================================================
// k_out: out[b][c][n] = h[b][n][c]. grid (64, 4, 2). Verified r2-r6 pattern.
__global__ __launch_bounds__(256) void k_out(const float* __restrict__ h,
                                             float* __restrict__ out) {
    __shared__ float hs_[64][33];
    const int t = threadIdx.x;
    const int n0 = blockIdx.x * 64, c0 = blockIdx.y * 32, b = blockIdx.z;
    for (int q = t; q < 2048; q += 256) {
        int nl = q >> 5, cl = q & 31;
        hs_[nl][cl] = h[(size_t)(b * NN + n0 + nl) * CC + c0 + cl];
    }
    __syncthreads();
    for (int q = t; q < 2048; q += 256) {
        int cl = q >> 6, nl = q & 63;
        out[(size_t)(b * CC + c0 + cl) * NN + n0 + nl] = hs_[nl][cl];
    }
}

// ===========================================================================
extern "C" void kernel_launch(void* const* d_in, const int* in_sizes, int n_in,
                              void* d_out, int out_size, void* d_ws, size_t ws_size,
                              hipStream_t stream) {
    const float* x    = (const float*)d_in[0];
    const float* G_w  = (const float*)d_in[1];
    const float* G_b  = (const float*)d_in[2];
    const float* th_w = (const float*)d_in[3];
    const float* th_b = (const float*)d_in[4];
    const float* ph_w = (const float*)d_in[5];
    const float* ph_b = (const float*)d_in[6];
    const float* r_w  = (const float*)d_in[7];
    const float* r_b  = (const float*)d_in[8];
    const float* gt_w = (const float*)d_in[9];
    const float* gt_b = (const float*)d_in[10];
    const float* gp_w = (const float*)d_in[11];
    const float* gp_b = (const float*)d_in[12];
    float* out = (float*)d_out;

    // Workspace layout (byte offsets, 256-aligned)
    char* ws = (char*)d_ws;
    size_t off = 0;
    auto alloc = [&](size_t bytes) {
        char* p = ws + off;
        off = (off + bytes + 255) & ~size_t(255);
        return p;
    };
    float* p_theta   = (float*)alloc((size_t)NN * DS * sizeof(float));
    float* p_phi     = (float*)alloc((size_t)NN * DS * sizeof(float));
    float* f_p       = (float*)alloc((size_t)NN * FS * sizeof(float));
    float* colnorm_p = (float*)alloc((size_t)EE * NSH * CPAD * sizeof(float));
    float* colnorm_f = (float*)alloc((size_t)3 * BB * EE * NSH * CPAD * sizeof(float));
    float* h         = (float*)alloc((size_t)BB * NN * CC * sizeof(float));
    float* T         = (float*)alloc((size_t)BB * NN * DS * sizeof(float));
    float* P         = (float*)alloc((size_t)BB * NN * DS * sizeof(float));
    float* Gx        = (float*)alloc((size_t)BB * NN * DS * sizeof(float));
    float* f         = (float*)alloc((size_t)BB * NN * FS * sizeof(float));
    (void)ws_size; (void)in_sizes; (void)n_in; (void)out_size;

    k_setup<<<512, 256, 0, stream>>>(x, gt_w, gt_b, gp_w, gp_b,
                                     p_theta, p_phi, colnorm_p, colnorm_f, h);
    // one-time geo f_p via the axis-decomposed kernel (b-extent 1)
    k_fax<<<dim3(256, 3, 1), 256, 0, stream>>>(p_theta, p_phi, f_p, colnorm_p);
    for (int r = 0; r < 3; ++r) {
        float* cn = colnorm_f + (size_t)r * BB * EE * NSH * CPAD;
        k_proj<<<768, 256, 0, stream>>>(h, th_w, th_b, ph_w, ph_b, G_w, G_b,
                                        T, P, Gx);
        k_fax<<<dim3(256, 3, BB), 256, 0, stream>>>(T, P, f, cn);
        k_agg<<<dim3(256, 3, BB), 256, 0, stream>>>(nullptr, f, f_p,
                                                    colnorm_p, cn, Gx,
                                                    r_w, r_b, h);
    }
    k_out<<<dim3(64, 4, 2), 256, 0, stream>>>(h, out);
}

// Round 17
// 165.619 us; speedup vs baseline: 1.7704x; 1.7704x over previous
//
#include <hip/hip_runtime.h>
#include <math.h>

// Problem constants
#define BB 2
#define CC 128
#define NN 4096            // D*H*W = 16*16*16
#define EE 46              // 16 + 15 + 15 neighbors
#define FS 48              // axis-major f stride: col = axis*16 + slot
#define DS 64              // DSIM = PSIM = GDIM = 64
#define CPAD 16            // dwords per shadow slot (one 64B line each)
#define NSH 16             // shadow copies per counter (atomic de-contention)
// colnorm layout: [b][e][NSH][CPAD] -> addr ((b*EE+e)*NSH + s)*CPAD

// ===========================================================================
// Setup: zero colnorms, neighbor table, h transpose. grid 512 x 256.
__global__ __launch_bounds__(256) void k_setup(
    const float* __restrict__ x,
    int* __restrict__ nbr,
    float* __restrict__ colnorm_p, float* __restrict__ colnorm_f,
    float* __restrict__ h)
{
    __shared__ float xs[32 * 65];
    const int t = threadIdx.x, bid = blockIdx.x;
    const int gtid = bid * 256 + t;

    if (gtid < EE * NSH * CPAD) colnorm_p[gtid] = 0.f;
    if (gtid < 3 * BB * EE * NSH * CPAD) colnorm_f[gtid] = 0.f;

    if (gtid < NN) {   // sorted 3-way merge of axis neighbor lists
        int n = gtid;
        int i = n >> 8, j = (n >> 4) & 15, k = n & 15;
        int ia = 0, ib = 0, ic = 0;
        for (int e = 0; e < EE; ++e) {
            int va = (ia < 16) ? ia * 256 + j * 16 + k : 0x7fffffff;
            int jb = ib + (ib >= j ? 1 : 0);
            int vb = (ib < 15) ? i * 256 + jb * 16 + k : 0x7fffffff;
            int kc = ic + (ic >= k ? 1 : 0);
            int vc = (ic < 15) ? i * 256 + j * 16 + kc : 0x7fffffff;
            int v;
            if (va < vb && va < vc)      { v = va; ++ia; }
            else if (vb < vc)            { v = vb; ++ib; }
            else                         { v = vc; ++ic; }
            nbr[n * EE + e] = v;
        }
    }
    {   // h[b][n][c] = x[b][c][n], one 64n x 32c tile per block
        int n0 = (bid & 63) * 64, c0 = ((bid >> 6) & 3) * 32, b = bid >> 8;
        for (int q = t; q < 2048; q += 256) {
            int cl = q >> 6, nl = q & 63;
            xs[cl * 65 + nl] = x[(size_t)(b * CC + c0 + cl) * NN + n0 + nl];
        }
        __syncthreads();
        for (int q = t; q < 2048; q += 256) {
            int nl = q >> 5, cl = q & 31;
            h[(size_t)(b * NN + n0 + nl) * CC + c0 + cl] = xs[cl * 65 + nl];
        }
    }
}

// ===========================================================================
// proj: [8192x128]x[128x192]^T GEMM. 32-row x 64-col tiles, BOTH operands
// LDS-staged (48 KB -> 3 blocks/CU), XOR-swizzled, 2x4 register blocking.
__global__ __launch_bounds__(256) void k_proj(
    const float* __restrict__ h,
    const float* __restrict__ th_w, const float* __restrict__ th_b,
    const float* __restrict__ ph_w, const float* __restrict__ ph_b,
    const float* __restrict__ G_w,  const float* __restrict__ G_b,
    float* __restrict__ T, float* __restrict__ P, float* __restrict__ Gx)
{
    __shared__ __align__(16) float smf[12288];   // 48 KB
    const int t = threadIdx.x;
    const int row0 = (blockIdx.x & 255) * 32;
    const int cgp = blockIdx.x >> 8;
    const float* w    = cgp == 0 ? th_w : cgp == 1 ? ph_w : G_w;
    const float* bias = cgp == 0 ? th_b : cgp == 1 ? ph_b : G_b;
    float* o          = cgp == 0 ? T    : cgp == 1 ? P    : Gx;
    float4* hs4 = (float4*)smf;              // [32][32] f4, XOR-swizzled
    float4* ws4 = (float4*)smf + 1024;       // [64][32] f4, XOR-swizzled
    const float4* h4 = (const float4*)h;
    const float4* w4 = (const float4*)w;
    for (int q = t; q < 1024; q += 256) {
        int row = q >> 5, kc = q & 31;
        hs4[row * 32 + (kc ^ row)] = h4[(size_t)(row0 + row) * 32 + kc];
    }
    for (int q = t; q < 2048; q += 256) {
        int row = q >> 5, kc = q & 31;
        ws4[row * 32 + (kc ^ (row & 31))] = w4[q];
    }
    __syncthreads();
    const int rt = t >> 4, m = t & 15;       // rows 2rt,2rt+1; cols m+16i
    float acc[2][4] = {{0, 0, 0, 0}, {0, 0, 0, 0}};
    for (int kc = 0; kc < 32; ++kc) {
        float4 a0 = hs4[(2 * rt) * 32 + (kc ^ (2 * rt))];
        float4 a1 = hs4[(2 * rt + 1) * 32 + (kc ^ (2 * rt + 1))];
        float4 wv[4];
#pragma unroll
        for (int i = 0; i < 4; ++i) {
            int c = m + 16 * i;
            wv[i] = ws4[c * 32 + (kc ^ (c & 31))];
        }
#pragma unroll
        for (int i = 0; i < 4; ++i) {
            acc[0][i] += a0.x * wv[i].x + a0.y * wv[i].y
                       + a0.z * wv[i].z + a0.w * wv[i].w;
            acc[1][i] += a1.x * wv[i].x + a1.y * wv[i].y
                       + a1.z * wv[i].z + a1.w * wv[i].w;
        }
    }
#pragma unroll
    for (int i = 0; i < 4; ++i) {
        float bv = bias[m + 16 * i];
#pragma unroll
        for (int rr = 0; rr < 2; ++rr)
            o[(size_t)(row0 + 2 * rt + rr) * DS + m + 16 * i] = acc[rr][i] + bv;
    }
}

// ===========================================================================
// axis helpers
__device__ __forceinline__ int axis_node(int axis, int line, int s) {
    if (axis == 0) return s * 256 + line;                           // D: line=(j,k)
    if (axis == 1) return (line >> 4) * 256 + s * 16 + (line & 15); // H: line=(i,k)
    return line * 16 + s;                                           // W: line=(i,j)
}

// ===========================================================================
// k_fax: axis-decomposed f, AXIS-MAJOR storage f[b][n][48] (col=axis*16+slot).
// Normal blocks (blockIdx.z < BB): stage T/P line tiles from global.
// Geo blocks (blockIdx.z == BB, round-0 launch only): compute the line's
// p_theta/p_phi rows INLINE from coordinates + geo weights (8 FLOP/elem) and
// produce the one-time f_p / colnorm_p instead. Identical body otherwise.
// Coalesced writes; sorted rank e used only for per-e sumsq; shadow-slot
// global atomics (chain 48, r15-verified).
__global__ __launch_bounds__(256) void k_fax(
    const float* __restrict__ T, const float* __restrict__ P,
    const float* __restrict__ gt_w, const float* __restrict__ gt_b,
    const float* __restrict__ gp_w, const float* __restrict__ gp_b,
    float* __restrict__ f, float* __restrict__ colnorm_f,
    float* __restrict__ f_p, float* __restrict__ colnorm_p)
{
    __shared__ __align__(16) float4 Ts4[272];    // [16][17]
    __shared__ __align__(16) float4 Ps4[272];
    __shared__ float sq[64];

    const int t = threadIdx.x;
    const int line = blockIdx.x, axis = blockIdx.y;
    const bool geo = (blockIdx.z == BB);
    const int b = geo ? 0 : blockIdx.z;
    float* dst = geo ? f_p : f;
    float* cn  = geo ? colnorm_p : colnorm_f;

    {
        int s = t >> 4, kc = t & 15;
        int nrow = axis_node(axis, line, s);
        if (!geo) {
            Ts4[s * 17 + kc] = ((const float4*)T)[((size_t)b * NN + nrow) * 16 + kc];
            Ps4[s * 17 + kc] = ((const float4*)P)[((size_t)b * NN + nrow) * 16 + kc];
        } else {
            int i = nrow >> 8, j = (nrow >> 4) & 15, k = nrow & 15;
            float p0 = i * (1.f / 15.f) - 0.5f;
            float p1 = j * (1.f / 15.f) - 0.5f;
            float p2 = k * (1.f / 15.f) - 0.5f;
            float tv[4], pv[4];
#pragma unroll
            for (int d = 0; d < 4; ++d) {
                int dim = kc * 4 + d;
                tv[d] = p0 * gt_w[dim * 3] + p1 * gt_w[dim * 3 + 1]
                      + p2 * gt_w[dim * 3 + 2] + gt_b[dim];
                pv[d] = p0 * gp_w[dim * 3] + p1 * gp_w[dim * 3 + 1]
                      + p2 * gp_w[dim * 3 + 2] + gp_b[dim];
            }
            Ts4[s * 17 + kc] = make_float4(tv[0], tv[1], tv[2], tv[3]);
            Ps4[s * 17 + kc] = make_float4(pv[0], pv[1], pv[2], pv[3]);
        }
    }
    if (t < 64) sq[t] = 0.f;
    __syncthreads();

    const int node = t >> 4, slot = t & 15;      // node-major: coalesced writes
    const int n = axis_node(axis, line, node);
    const int m = axis_node(axis, line, slot);
    const int jj = (n >> 4) & 15, kk = n & 15;
    bool valid = !((axis == 1 && slot == jj) || (axis == 2 && slot == kk));

    float dot = 0.f;
#pragma unroll
    for (int kc = 0; kc < 16; ++kc) {
        float4 a = Ts4[node * 17 + kc];
        float4 p = Ps4[slot * 17 + kc];
        dot += a.x * p.x + a.y * p.y + a.z * p.z + a.w * p.w;
    }

    if (valid) {
        dst[((size_t)b * NN + n) * FS + axis * 16 + slot] = dot;
        // sorted rank of m in n's merged neighbor list (for per-e sumsq)
        const int jk = n & 255, base = n & ~255;
        int d = m - jk;
        int cD = d <= 0 ? 0 : min(16, (d + 255) >> 8);
        int hd = m - base - kk;
        int cHr = hd <= 0 ? 0 : min(16, (hd + 15) >> 4);
        int cH = cHr - (jj < cHr ? 1 : 0);
        int wd = m - (n - kk);
        int cWr = wd <= 0 ? 0 : min(16, wd);
        int cW = cWr - (kk < cWr ? 1 : 0);
        int e = cD + cH + cW;
        atomicAdd(&sq[e], dot * dot);
    }
    __syncthreads();
    if (t < EE)
        atomicAdd(cn + ((size_t)(b * EE + t) * NSH + (line & (NSH - 1))) * CPAD,
                  sq[t]);
}

// ===========================================================================
// k_agg: axis-decomposed dense aggregation (r15-verified). f/f_p read via the
// (ax,slot) classification; colnorm factors summed over the NSH shadow slots.
__global__ __launch_bounds__(256) void k_agg(
    const int* __restrict__ nbr,
    const float* __restrict__ f, const float* __restrict__ f_p,
    const float* __restrict__ colnorm_p, const float* __restrict__ colnorm_f,
    const float* __restrict__ Gx, float* __restrict__ y)
{
    __shared__ __align__(16) float Gl[16 * 64];   // 4 KB
    __shared__ float wmat[256];                   // [16 nodes][16 slots]
    __shared__ float nf[64], np[64];

    const int t = threadIdx.x;
    const int line = blockIdx.x, axis = blockIdx.y, b = blockIdx.z;

    if (t < EE) {
        float sf = 0.f, sp = 0.f;
#pragma unroll
        for (int s = 0; s < NSH; ++s) {
            sf += colnorm_f[((size_t)(b * EE + t) * NSH + s) * CPAD];
            sp += colnorm_p[((size_t)t * NSH + s) * CPAD];
        }
        nf[t] = 1.f / (1e-6f + sqrtf(sf));
        np[t] = 1.f / (1e-6f + sqrtf(sp));
    }
    wmat[t] = 0.f;
    {
        int s = t >> 4, c4 = t & 15;
        int nrow = axis_node(axis, line, s);
        ((float4*)Gl)[s * 16 + c4] =
            ((const float4*)Gx)[((size_t)b * NN + nrow) * 16 + c4];
    }
    __syncthreads();

    const int wv = t >> 6, l = t & 63;
    for (int ii = 0; ii < 4; ++ii) {
        int sn = wv * 4 + ii;
        int n = axis_node(axis, line, sn);
        float fvv = -INFINITY; int ax = 0, slot = 0;
        if (l < EE) {
            int m = nbr[n * EE + l];
            int x = m ^ n;
            if (x == 0)       { ax = 0; slot = n >> 8; }         // self: D list
            else if (x < 16)  { ax = 2; slot = m & 15; }         // W
            else if (x < 256) { ax = 1; slot = (m >> 4) & 15; }  // H
            else              { ax = 0; slot = m >> 8; }         // D
            int col = ax * 16 + slot;
            float fpv = f_p[(size_t)n * FS + col] * np[l];
            fpv = fpv > 0.f ? fpv : 0.f;
            fvv = f[(size_t)(b * NN + n) * FS + col] * nf[l] + fpv;
        }
        float mx = fvv;
        for (int o = 32; o; o >>= 1) mx = fmaxf(mx, __shfl_down(mx, o));
        mx = __shfl(mx, 0);
        float ex = (l < EE) ? expf(fvv - mx) : 0.f;
        float sm = ex;
        for (int o = 32; o; o >>= 1) sm += __shfl_down(sm, o);
        sm = __shfl(sm, 0);
        if (l < EE && ax == axis) wmat[sn * 16 + slot] = ex / sm;
    }
    __syncthreads();

    // dense 16x16x64: wave wv handles nodes wv*4..wv*4+3, lane l = dim
    float acc[4] = {0.f, 0.f, 0.f, 0.f};
    for (int s = 0; s < 16; ++s) {
        float gv = Gl[s * 64 + l];
        acc[0] += wmat[(wv * 4 + 0) * 16 + s] * gv;
        acc[1] += wmat[(wv * 4 + 1) * 16 + s] * gv;
        acc[2] += wmat[(wv * 4 + 2) * 16 + s] * gv;
        acc[3] += wmat[(wv * 4 + 3) * 16 + s] * gv;
    }
    float* ya = y + ((size_t)axis * BB + b) * NN * DS;
#pragma unroll
    for (int kk = 0; kk < 4; ++kk) {
        int n = axis_node(axis, line, wv * 4 + kk);
        ya[(size_t)n * DS + l] = acc[kk];
    }
}

// ===========================================================================
// k_epi: delta = (y_D+y_H+y_W) @ r_w^T + r_b + h (residual). r15-verified.
template <int LAST>
__global__ __launch_bounds__(256) void k_epi(
    const float* __restrict__ y, const float* __restrict__ r_w,
    const float* __restrict__ r_b,
    float* __restrict__ h, float* __restrict__ out)
{
    __shared__ __align__(16) float smf[6528];    // 26112 B
    float4* ys4  = (float4*)smf;                 // [32][17] f4 (dw 0..2175)
    float4* rws4 = (float4*)smf + 544;           // [64][17] f4 (dw 2176..6527)
    float*  dls  = smf;                          // LAST: reuse as [32][68]

    const int t = threadIdx.x;
    const int rt0 = blockIdx.x * 32;             // global row (b*NN+n)
    const int c0 = blockIdx.y * 64;
    const float4* y4  = (const float4*)y;
    const float4* rw4 = (const float4*)r_w;
    for (int q = t; q < 512; q += 256) {
        int row = q >> 4, kc = q & 15;
        float4 a = y4[(size_t)(rt0 + row) * 16 + kc];
        float4 bb = y4[((size_t)BB * NN + rt0 + row) * 16 + kc];
        float4 c = y4[((size_t)2 * BB * NN + rt0 + row) * 16 + kc];
        float4 s;
        s.x = a.x + bb.x + c.x; s.y = a.y + bb.y + c.y;
        s.z = a.z + bb.z + c.z; s.w = a.w + bb.w + c.w;
        ys4[row * 17 + kc] = s;
    }
    for (int q = t; q < 1024; q += 256) {
        int row = q >> 4, kc = q & 15;
        rws4[row * 17 + kc] = rw4[(size_t)(c0 + row) * 16 + kc];
    }
    __syncthreads();

    const int rt = t >> 4, m = t & 15;           // rows 2rt,2rt+1; cols m+16i
    float acc[2][4] = {{0, 0, 0, 0}, {0, 0, 0, 0}};
    for (int kc = 0; kc < 16; ++kc) {
        float4 a0 = ys4[(2 * rt) * 17 + kc];
        float4 a1 = ys4[(2 * rt + 1) * 17 + kc];
        float4 wv[4];
#pragma unroll
        for (int i = 0; i < 4; ++i)
            wv[i] = rws4[(m + 16 * i) * 17 + kc];
#pragma unroll
        for (int i = 0; i < 4; ++i) {
            acc[0][i] += a0.x * wv[i].x + a0.y * wv[i].y
                       + a0.z * wv[i].z + a0.w * wv[i].w;
            acc[1][i] += a1.x * wv[i].x + a1.y * wv[i].y
                       + a1.z * wv[i].z + a1.w * wv[i].w;
        }
    }

    if (!LAST) {
#pragma unroll
        for (int rr = 0; rr < 2; ++rr) {
            size_t r = (size_t)rt0 + 2 * rt + rr;
#pragma unroll
            for (int i = 0; i < 4; ++i) {
                int c = c0 + m + 16 * i;
                h[r * CC + c] += acc[rr][i] + r_b[c];
            }
        }
    } else {
        float res[2][4];
#pragma unroll
        for (int rr = 0; rr < 2; ++rr) {
            size_t r = (size_t)rt0 + 2 * rt + rr;
#pragma unroll
            for (int i = 0; i < 4; ++i) {
                int c = c0 + m + 16 * i;
                res[rr][i] = h[r * CC + c] + acc[rr][i] + r_b[c];
            }
        }
        __syncthreads();                         // done reading ys4 region
#pragma unroll
        for (int rr = 0; rr < 2; ++rr)
#pragma unroll
            for (int i = 0; i < 4; ++i)
                dls[(2 * rt + rr) * 68 + m + 16 * i] = res[rr][i];
        __syncthreads();
        const int b = rt0 >> 12, n0g = rt0 & (NN - 1);
        for (int q = t; q < 2048; q += 256) {
            int cl = q >> 5, nl = q & 31;
            out[(size_t)(b * CC + c0 + cl) * NN + n0g + nl] = dls[nl * 68 + cl];
        }
    }
}

// ===========================================================================
extern "C" void kernel_launch(void* const* d_in, const int* in_sizes, int n_in,
                              void* d_out, int out_size, void* d_ws, size_t ws_size,
                              hipStream_t stream) {
    const float* x    = (const float*)d_in[0];
    const float* G_w  = (const float*)d_in[1];
    const float* G_b  = (const float*)d_in[2];
    const float* th_w = (const float*)d_in[3];
    const float* th_b = (const float*)d_in[4];
    const float* ph_w = (const float*)d_in[5];
    const float* ph_b = (const float*)d_in[6];
    const float* r_w  = (const float*)d_in[7];
    const float* r_b  = (const float*)d_in[8];
    const float* gt_w = (const float*)d_in[9];
    const float* gt_b = (const float*)d_in[10];
    const float* gp_w = (const float*)d_in[11];
    const float* gp_b = (const float*)d_in[12];
    float* out = (float*)d_out;

    // Workspace layout (byte offsets, 256-aligned)
    char* ws = (char*)d_ws;
    size_t off = 0;
    auto alloc = [&](size_t bytes) {
        char* p = ws + off;
        off = (off + bytes + 255) & ~size_t(255);
        return p;
    };
    int*   nbr       = (int*)  alloc((size_t)NN * EE * sizeof(int));
    float* f_p       = (float*)alloc((size_t)NN * FS * sizeof(float));
    float* colnorm_p = (float*)alloc((size_t)EE * NSH * CPAD * sizeof(float));
    float* colnorm_f = (float*)alloc((size_t)3 * BB * EE * NSH * CPAD * sizeof(float));
    float* h         = (float*)alloc((size_t)BB * NN * CC * sizeof(float));
    float* T         = (float*)alloc((size_t)BB * NN * DS * sizeof(float));
    float* P         = (float*)alloc((size_t)BB * NN * DS * sizeof(float));
    float* Gx        = (float*)alloc((size_t)BB * NN * DS * sizeof(float));
    float* f         = (float*)alloc((size_t)BB * NN * FS * sizeof(float));
    float* y         = (float*)alloc((size_t)3 * BB * NN * DS * sizeof(float));
    (void)ws_size; (void)in_sizes; (void)n_in; (void)out_size;

    k_setup<<<512, 256, 0, stream>>>(x, nbr, colnorm_p, colnorm_f, h);
    for (int r = 0; r < 3; ++r) {
        float* cn = colnorm_f + (size_t)r * BB * EE * NSH * CPAD;
        k_proj<<<768, 256, 0, stream>>>(h, th_w, th_b, ph_w, ph_b, G_w, G_b,
                                        T, P, Gx);
        // round 0 carries the one-time geo f_p blocks (blockIdx.z == BB)
        int zext = (r == 0) ? BB + 1 : BB;
        k_fax<<<dim3(256, 3, zext), 256, 0, stream>>>(T, P, gt_w, gt_b,
                                                      gp_w, gp_b, f, cn,
                                                      f_p, colnorm_p);
        k_agg<<<dim3(256, 3, BB), 256, 0, stream>>>(nbr, f, f_p, colnorm_p, cn,
                                                    Gx, y);
        if (r < 2)
            k_epi<0><<<dim3(256, 2), 256, 0, stream>>>(y, r_w, r_b, h, out);
        else
            k_epi<1><<<dim3(256, 2), 256, 0, stream>>>(y, r_w, r_b, h, out);
    }
}